// Round 12
// baseline (207.097 us; speedup 1.0000x reference)
//
#include <hip/hip_runtime.h>

#define D_DIM 1024
#define B_HALF 4096
#define NROWS 8192
#define INV_TEMP 10.0f
#define NKT 32      // 1024 / 32 K-tiles
#define NBIG 512    // 528 upper-tri 256-tiles minus the 16 (rt, rt+16) tiles
#define NBLK 576    // + 64 quadrant 128-tiles dispatched last

typedef __bf16 bf16x8 __attribute__((ext_vector_type(8)));
typedef float floatx4 __attribute__((ext_vector_type(4)));

#define MFMA16 __builtin_amdgcn_mfma_f32_16x16x32_bf16
#define AS1 const __attribute__((address_space(1))) unsigned int*
#define AS3 __attribute__((address_space(3))) unsigned int*

__device__ __forceinline__ unsigned short f32_to_bf16(float f) {
    union { float f; unsigned u; } v; v.f = f;
    unsigned r = 0x7FFFu + ((v.u >> 16) & 1u);
    return (unsigned short)((v.u + r) >> 16);
}

// Kernel 1: wave-per-row L2-normalize. Each 64-lane wave owns one FULL row:
// 4 x float4 per lane (64*16 = 1024 elems). No barriers, no LDS.
__global__ __launch_bounds__(256) void normalize_kernel(
    const float* __restrict__ z1, const float* __restrict__ z2,
    unsigned short* __restrict__ R, float* __restrict__ S)
{
    const int tid = threadIdx.x;
    const int lane = tid & 63;
    const int row = blockIdx.x * 4 + (tid >> 6);
    const float* src = (row < B_HALF) ? (z1 + (size_t)row * D_DIM)
                                      : (z2 + (size_t)(row - B_HALF) * D_DIM);
    const float4* s4 = (const float4*)src;
    float4 v0 = s4[lane], v1 = s4[64 + lane], v2 = s4[128 + lane], v3 = s4[192 + lane];
    if (lane == 0) S[row] = 0.0f;
    float ss = v0.x*v0.x + v0.y*v0.y + v0.z*v0.z + v0.w*v0.w
             + v1.x*v1.x + v1.y*v1.y + v1.z*v1.z + v1.w*v1.w
             + v2.x*v2.x + v2.y*v2.y + v2.z*v2.z + v2.w*v2.w
             + v3.x*v3.x + v3.y*v3.y + v3.z*v3.z + v3.w*v3.w;
    ss += __shfl_xor(ss, 1);
    ss += __shfl_xor(ss, 2);
    ss += __shfl_xor(ss, 4);
    ss += __shfl_xor(ss, 8);
    ss += __shfl_xor(ss, 16);
    ss += __shfl_xor(ss, 32);
    float scale = 1.0f / fmaxf(sqrtf(ss), 1e-12f);
    ushort4* dst = (ushort4*)(R + (size_t)row * D_DIM);
    float4 vv[4] = {v0, v1, v2, v3};
    #pragma unroll
    for (int i = 0; i < 4; ++i) {
        ushort4 o;
        o.x = f32_to_bf16(vv[i].x * scale);
        o.y = f32_to_bf16(vv[i].y * scale);
        o.z = f32_to_bf16(vv[i].z * scale);
        o.w = f32_to_bf16(vv[i].w * scale);
        dst[i * 64 + lane] = o;
    }
}

// Kernel 2, mixed grid (r10-verified makespan win):
//  blocks [0,512): 256x256 upper-tri tiles excluding the 16 (rt, rt+16)
//    pos-band tiles. BK=32, 64 KiB double-buffered LDS for A ONLY
//    (2 blocks/CU co-resident); B fragments read directly global->reg
//    (L1/L2-resident slab) to take B off the LDS port (r10 measured
//    LDS-port-bound: model 89 us vs measured 93). One vmcnt(0)+barrier
//    per K-tile. Involution swizzle on A (slot ^= (row>>1)&3, measured 0
//    conflicts).
//  blocks [512,576): the 16 removed tiles as 64 128x128 quadrants
//    (never diagonal; carry all pos pairs), dispatched last (backfill).
//  Epilogue: row/col exp-sums reduced in LDS, atomicAdd into S.
__global__ __launch_bounds__(512, 2) void gemm_lse_kernel(
    const unsigned short* __restrict__ R,
    float* __restrict__ S, float* __restrict__ pos)
{
    __shared__ unsigned short lds[2][2][256 * 32];   // 64 KiB ([d][1] used by small path)

    const int tid = threadIdx.x;
    const int wave = tid >> 6, lane = tid & 63;
    const int lm = lane & 15, lq = lane >> 4;
    const int wm = wave >> 2, wn = wave & 3;         // 2 x 4 wave grid
    // staging lane map: 16 rows x 4 slots per issue; involution swizzle
    const int sRow = lane >> 2;                      // 0..15
    const int sCol = (lane & 3) ^ ((sRow >> 1) & 3); // swizzled global slot
    const int sk = (lq ^ ((lm >> 1) & 3)) * 8;       // swizzled read k-slot

    if (blockIdx.x < NBIG) {
        // ---- BIG PATH: 256x256, BK=32, A-in-LDS / B-from-global ----
        int t = blockIdx.x;
        #pragma unroll
        for (int i = 0; i < 16; ++i) {               // skip the 16 holes
            const int h = 32 * i - (i * (i - 1)) / 2 + 16;
            if (t >= h) ++t;
        }
        int rt = 0;
        while (t >= 32 - rt) { t -= 32 - rt; ++rt; }
        const int ct = rt + t;
        const bool isDiag = (rt == ct);
        const int row0 = rt * 256, col0 = ct * 256;

        const unsigned short* __restrict__ gA = R + (size_t)row0 * D_DIM;
        const unsigned short* __restrict__ gB = R + (size_t)col0 * D_DIM;
        const int aBase = (wm * 128 + lm) * 32 + sk;

        floatx4 acc[8][4] = {};

#define BSTAGE(d, kk) \
        { _Pragma("unroll") for (int i = 0; i < 2; ++i) { \
            __builtin_amdgcn_global_load_lds( \
              (AS1)(gA + (size_t)(wave * 32 + i * 16 + sRow) * D_DIM + (kk) + sCol * 8), \
              (AS3)(&lds[d][0][(wave * 32 + i * 16) * 32]), 16, 0, 0); } }

        BSTAGE(0, 0)
        asm volatile("s_waitcnt vmcnt(0)" ::: "memory");
        __builtin_amdgcn_s_barrier();

        for (int kt = 0; kt < NKT; ++kt) {
            const int buf = kt & 1;
            const unsigned short* As = &lds[buf][0][0];
            if (kt + 1 < NKT) BSTAGE(buf ^ 1, (kt + 1) * 32)

            // B fragments straight from global (L1/L2-resident panel slab)
            bf16x8 bf[4];
            const unsigned short* gBk = gB + kt * 32 + lq * 8;
            #pragma unroll
            for (int ni = 0; ni < 4; ++ni)
                bf[ni] = *(const bf16x8*)(gBk + (size_t)(wn * 64 + ni * 16 + lm) * D_DIM);

            bf16x8 af[8];
            #pragma unroll
            for (int mi = 0; mi < 8; ++mi)
                af[mi] = *(const bf16x8*)(As + aBase + mi * 512);

            __builtin_amdgcn_s_setprio(1);
            #pragma unroll
            for (int mi = 0; mi < 8; ++mi)
                #pragma unroll
                for (int ni = 0; ni < 4; ++ni)
                    acc[mi][ni] = MFMA16(af[mi], bf[ni], acc[mi][ni], 0, 0, 0);
            __builtin_amdgcn_s_setprio(0);

            asm volatile("s_waitcnt vmcnt(0)" ::: "memory");
            __builtin_amdgcn_s_barrier();
        }

        float* rowsum = (float*)&lds[0][0][0];   // [4][256]
        float* colsum = rowsum + 4 * 256;        // [2][256]
        float ecol[4] = {0.0f, 0.0f, 0.0f, 0.0f};
        #pragma unroll
        for (int mi = 0; mi < 8; ++mi) {
            const int rloc = wm * 128 + mi * 16 + lq * 4;
            #pragma unroll
            for (int reg = 0; reg < 4; ++reg) {
                const int gr = row0 + rloc + reg;
                float esum = 0.0f;
                #pragma unroll
                for (int ni = 0; ni < 4; ++ni) {
                    const int gc = col0 + wn * 64 + ni * 16 + lm;
                    float s = acc[mi][ni][reg] * INV_TEMP;
                    if (gc == gr + B_HALF) { pos[gr] = s; pos[gc] = s; }
                    float e = (gc == gr) ? 0.0f : __expf(s);
                    esum += e;
                    ecol[ni] += e;
                }
                esum += __shfl_xor(esum, 1);
                esum += __shfl_xor(esum, 2);
                esum += __shfl_xor(esum, 4);
                esum += __shfl_xor(esum, 8);
                if (lm == 0) rowsum[wn * 256 + rloc + reg] = esum;
            }
        }
        #pragma unroll
        for (int ni = 0; ni < 4; ++ni) {
            ecol[ni] += __shfl_xor(ecol[ni], 16);
            ecol[ni] += __shfl_xor(ecol[ni], 32);
        }
        if (lq == 0 && !isDiag) {
            #pragma unroll
            for (int ni = 0; ni < 4; ++ni)
                colsum[wm * 256 + wn * 64 + ni * 16 + lm] = ecol[ni];
        }
        __syncthreads();
        if (tid < 256) {
            float rs = rowsum[tid] + rowsum[256 + tid]
                     + rowsum[512 + tid] + rowsum[768 + tid];
            atomicAdd(&S[row0 + tid], rs);
            if (!isDiag) {
                float cs = colsum[tid] + colsum[256 + tid];
                atomicAdd(&S[col0 + tid], cs);
            }
        }
    } else {
        // ---- SMALL PATH: 128x128 quadrants of the 16 (rt, rt+16) tiles ----
        const int s = blockIdx.x - NBIG;
        const int p = s >> 2, qr = (s >> 1) & 1, qc = s & 1;
        const int row0 = (2 * p + qr) * 128;
        const int col0 = (2 * p + 32 + qc) * 128;   // never diagonal

        const unsigned short* __restrict__ gA = R + (size_t)row0 * D_DIM;
        const unsigned short* __restrict__ gB = R + (size_t)col0 * D_DIM;
        const int aBase = (wm * 64 + lm) * 32 + sk;
        const int bBase = (wn * 32 + lm) * 32 + sk;

        floatx4 acc[4][2] = {};

#define SSTAGE(d, kk) \
        { __builtin_amdgcn_global_load_lds( \
            (AS1)(gA + (size_t)(wave * 16 + sRow) * D_DIM + (kk) + sCol * 8), \
            (AS3)(&lds[d][0][(wave * 16) * 32]), 16, 0, 0); \
          __builtin_amdgcn_global_load_lds( \
            (AS1)(gB + (size_t)(wave * 16 + sRow) * D_DIM + (kk) + sCol * 8), \
            (AS3)(&lds[d][1][(wave * 16) * 32]), 16, 0, 0); }

        SSTAGE(0, 0)
        asm volatile("s_waitcnt vmcnt(0)" ::: "memory");
        __builtin_amdgcn_s_barrier();

        for (int kt = 0; kt < NKT; ++kt) {
            const int buf = kt & 1;
            const unsigned short* As = &lds[buf][0][0];
            const unsigned short* Bs = &lds[buf][1][0];
            if (kt + 1 < NKT) SSTAGE(buf ^ 1, (kt + 1) * 32)

            bf16x8 af[4], bf[2];
            #pragma unroll
            for (int mi = 0; mi < 4; ++mi)
                af[mi] = *(const bf16x8*)(As + aBase + mi * 512);
            #pragma unroll
            for (int ni = 0; ni < 2; ++ni)
                bf[ni] = *(const bf16x8*)(Bs + bBase + ni * 512);

            __builtin_amdgcn_s_setprio(1);
            #pragma unroll
            for (int mi = 0; mi < 4; ++mi)
                #pragma unroll
                for (int ni = 0; ni < 2; ++ni)
                    acc[mi][ni] = MFMA16(af[mi], bf[ni], acc[mi][ni], 0, 0, 0);
            __builtin_amdgcn_s_setprio(0);

            asm volatile("s_waitcnt vmcnt(0)" ::: "memory");
            __builtin_amdgcn_s_barrier();
        }

        float* rowsum = (float*)&lds[0][0][0];   // [4][128]
        float* colsum = rowsum + 4 * 128;        // [2][128]
        float ecol[2] = {0.0f, 0.0f};
        #pragma unroll
        for (int mi = 0; mi < 4; ++mi) {
            const int rloc = wm * 64 + mi * 16 + lq * 4;
            #pragma unroll
            for (int reg = 0; reg < 4; ++reg) {
                const int gr = row0 + rloc + reg;
                float esum = 0.0f;
                #pragma unroll
                for (int ni = 0; ni < 2; ++ni) {
                    const int gc = col0 + wn * 32 + ni * 16 + lm;
                    float s = acc[mi][ni][reg] * INV_TEMP;
                    if (gc == gr + B_HALF) { pos[gr] = s; pos[gc] = s; }
                    float e = __expf(s);     // never on the main diagonal
                    esum += e;
                    ecol[ni] += e;
                }
                esum += __shfl_xor(esum, 1);
                esum += __shfl_xor(esum, 2);
                esum += __shfl_xor(esum, 4);
                esum += __shfl_xor(esum, 8);
                if (lm == 0) rowsum[wn * 128 + rloc + reg] = esum;
            }
        }
        #pragma unroll
        for (int ni = 0; ni < 2; ++ni) {
            ecol[ni] += __shfl_xor(ecol[ni], 16);
            ecol[ni] += __shfl_xor(ecol[ni], 32);
        }
        if (lq == 0) {
            #pragma unroll
            for (int ni = 0; ni < 2; ++ni)
                colsum[wm * 128 + wn * 32 + ni * 16 + lm] = ecol[ni];
        }
        __syncthreads();
        if (tid < 128) {
            float rs = rowsum[tid] + rowsum[128 + tid]
                     + rowsum[256 + tid] + rowsum[384 + tid];
            atomicAdd(&S[row0 + tid], rs);
            float cs = colsum[tid] + colsum[128 + tid];
            atomicAdd(&S[col0 + tid], cs);
        }
    }
}

// Kernel 3: single block; loss = mean(log1p(S * exp(-pos))).
__global__ __launch_bounds__(1024) void finalize_kernel(
    const float* __restrict__ S, const float* __restrict__ pos,
    float* __restrict__ out)
{
    const int tid = threadIdx.x;
    float local = 0.0f;
    #pragma unroll
    for (int i = 0; i < 8; ++i) {
        const int r = i * 1024 + tid;
        local += log1pf(S[r] * __expf(-pos[r]));
    }
    #pragma unroll
    for (int off = 32; off > 0; off >>= 1) local += __shfl_down(local, off);
    __shared__ float ws[16];
    if ((tid & 63) == 0) ws[tid >> 6] = local;
    __syncthreads();
    if (tid == 0) {
        float tot = 0.0f;
        #pragma unroll
        for (int i = 0; i < 16; ++i) tot += ws[i];
        out[0] = tot * (1.0f / 8192.0f);
    }
}

extern "C" void kernel_launch(void* const* d_in, const int* in_sizes, int n_in,
                              void* d_out, int out_size, void* d_ws, size_t ws_size,
                              hipStream_t stream)
{
    const float* z1 = (const float*)d_in[0];
    const float* z2 = (const float*)d_in[1];
    float* out = (float*)d_out;
    char* ws = (char*)d_ws;
    unsigned short* R = (unsigned short*)ws;                        // 16 MiB bf16 reps
    float* pos = (float*)(ws + (size_t)16 * 1024 * 1024);           // 32 KiB [8192]
    float* S   = (float*)(ws + (size_t)16 * 1024 * 1024 + 65536);   // 32 KiB [8192]

    normalize_kernel<<<2048, 256, 0, stream>>>(z1, z2, R, S);
    gemm_lse_kernel<<<NBLK, 512, 0, stream>>>(R, S, pos);
    finalize_kernel<<<1, 1024, 0, stream>>>(S, pos, out);
}

// Round 13
// 184.042 us; speedup vs baseline: 1.1253x; 1.1253x over previous
//
#include <hip/hip_runtime.h>

#define D_DIM 1024
#define B_HALF 4096
#define NROWS 8192
#define INV_T8 (10.0f / 256.0f)   // temperature 0.1, fp8 stored as 16x values
#define NKT 32      // 1024 / 32 K-tiles
#define NBIG 512    // 528 upper-tri 256-tiles minus the 16 (rt, rt+16) tiles
#define NBLK 576    // + 64 quadrant 128-tiles dispatched last

typedef float floatx4 __attribute__((ext_vector_type(4)));

#define MFMA8 __builtin_amdgcn_mfma_f32_16x16x32_fp8_fp8
#define AS1 const __attribute__((address_space(1))) unsigned int*
#define AS3 __attribute__((address_space(3))) unsigned int*

// Kernel 1: wave-per-row L2-normalize -> fp8 e4m3 R8 (values x16); zero S.
// Each 64-lane wave owns one full row (4 x float4 per lane).
__global__ __launch_bounds__(256) void normalize_kernel(
    const float* __restrict__ z1, const float* __restrict__ z2,
    unsigned char* __restrict__ R8, float* __restrict__ S)
{
    const int tid = threadIdx.x;
    const int lane = tid & 63;
    const int row = blockIdx.x * 4 + (tid >> 6);
    const float* src = (row < B_HALF) ? (z1 + (size_t)row * D_DIM)
                                      : (z2 + (size_t)(row - B_HALF) * D_DIM);
    const float4* s4 = (const float4*)src;
    float4 v0 = s4[lane], v1 = s4[64 + lane], v2 = s4[128 + lane], v3 = s4[192 + lane];
    if (lane == 0) S[row] = 0.0f;
    float ss = v0.x*v0.x + v0.y*v0.y + v0.z*v0.z + v0.w*v0.w
             + v1.x*v1.x + v1.y*v1.y + v1.z*v1.z + v1.w*v1.w
             + v2.x*v2.x + v2.y*v2.y + v2.z*v2.z + v2.w*v2.w
             + v3.x*v3.x + v3.y*v3.y + v3.z*v3.z + v3.w*v3.w;
    ss += __shfl_xor(ss, 1);
    ss += __shfl_xor(ss, 2);
    ss += __shfl_xor(ss, 4);
    ss += __shfl_xor(ss, 8);
    ss += __shfl_xor(ss, 16);
    ss += __shfl_xor(ss, 32);
    float scale = 16.0f / fmaxf(sqrtf(ss), 1e-12f);   // x16: clear of e4m3 denormals
    int* dst = (int*)(R8 + (size_t)row * D_DIM);
    float4 vv[4] = {v0, v1, v2, v3};
    #pragma unroll
    for (int i = 0; i < 4; ++i) {
        int w = __builtin_amdgcn_cvt_pk_fp8_f32(vv[i].x * scale, vv[i].y * scale, 0, 0);
        w = __builtin_amdgcn_cvt_pk_fp8_f32(vv[i].z * scale, vv[i].w * scale, w, 1);
        dst[i * 64 + lane] = w;
    }
}

// Kernel 2, mixed grid (r10-verified makespan win), fp8 operands:
//  blocks [0,512): 256x256 upper-tri tiles excluding the 16 (rt, rt+16)
//    pos-band tiles. BK=32, A+B fp8 in 32 KiB double-buffered LDS (halved
//    LDS-port traffic vs bf16 r10, which was port-bound at 93 us).
//    Natural layout: 32 B rows give pigeonhole-minimal bank spread for b64
//    reads (granule = (lm&3)*4+lq covers all 16), no swizzle needed.
//    One vmcnt(0)+barrier per K-tile; 2+ blocks/CU co-resident.
//  blocks [512,576): the 16 removed tiles as 64 128x128 quadrants
//    (never diagonal; carry all pos pairs), dispatched last (backfill).
//  Epilogue: row/col exp-sums reduced in LDS, atomicAdd into S.
__global__ __launch_bounds__(512, 2) void gemm_lse_kernel(
    const unsigned char* __restrict__ R8,
    float* __restrict__ S, float* __restrict__ pos)
{
    __shared__ unsigned char lds8[2][2][256 * 32];   // 32 KiB

    const int tid = threadIdx.x;
    const int wave = tid >> 6, lane = tid & 63;
    const int lm = lane & 15, lq = lane >> 4;
    const int wm = wave >> 2, wn = wave & 3;         // 2 x 4 wave grid

    if (blockIdx.x < NBIG) {
        // ---- BIG PATH: 256x256, BK=32 ----
        int t = blockIdx.x;
        #pragma unroll
        for (int i = 0; i < 16; ++i) {               // skip the 16 holes
            const int h = 32 * i - (i * (i - 1)) / 2 + 16;
            if (t >= h) ++t;
        }
        int rt = 0;
        while (t >= 32 - rt) { t -= 32 - rt; ++rt; }
        const int ct = rt + t;
        const bool isDiag = (rt == ct);
        const int row0 = rt * 256, col0 = ct * 256;

        const unsigned char* __restrict__ gA = R8 + (size_t)row0 * D_DIM;
        const unsigned char* __restrict__ gB = R8 + (size_t)col0 * D_DIM;

        floatx4 acc[8][4] = {};

        // one issue = 64 lanes x 16B = 32 rows x 32B; wave w stages rows
        // w*32..+32 of A and of B (2 issues/wave). lane -> row w*32+(l>>1),
        // half (l&1)*16. Linear LDS dest == linear global (no swizzle).
#define BSTAGE(d, kk) \
        { __builtin_amdgcn_global_load_lds( \
            (AS1)(gA + (size_t)(wave * 32 + (lane >> 1)) * D_DIM + (kk) + (lane & 1) * 16), \
            (AS3)(&lds8[d][0][wave * 1024]), 16, 0, 0); \
          __builtin_amdgcn_global_load_lds( \
            (AS1)(gB + (size_t)(wave * 32 + (lane >> 1)) * D_DIM + (kk) + (lane & 1) * 16), \
            (AS3)(&lds8[d][1][wave * 1024]), 16, 0, 0); }

        BSTAGE(0, 0)
        asm volatile("s_waitcnt vmcnt(0)" ::: "memory");
        __builtin_amdgcn_s_barrier();

        for (int kt = 0; kt < NKT; ++kt) {
            const int buf = kt & 1;
            const unsigned char* As = &lds8[buf][0][0];
            const unsigned char* Bs = &lds8[buf][1][0];
            if (kt + 1 < NKT) BSTAGE(buf ^ 1, (kt + 1) * 32)

            long af[8], bf[4];
            #pragma unroll
            for (int mi = 0; mi < 8; ++mi)
                af[mi] = *(const long*)(As + (wm * 128 + mi * 16 + lm) * 32 + lq * 8);
            #pragma unroll
            for (int ni = 0; ni < 4; ++ni)
                bf[ni] = *(const long*)(Bs + (wn * 64 + ni * 16 + lm) * 32 + lq * 8);

            __builtin_amdgcn_s_setprio(1);
            #pragma unroll
            for (int mi = 0; mi < 8; ++mi)
                #pragma unroll
                for (int ni = 0; ni < 4; ++ni)
                    acc[mi][ni] = MFMA8(af[mi], bf[ni], acc[mi][ni], 0, 0, 0);
            __builtin_amdgcn_s_setprio(0);

            asm volatile("s_waitcnt vmcnt(0)" ::: "memory");
            __builtin_amdgcn_s_barrier();
        }

        float* rowsum = (float*)&lds8[0][0][0];   // [4][256]
        float* colsum = rowsum + 4 * 256;         // [2][256]
        float ecol[4] = {0.0f, 0.0f, 0.0f, 0.0f};
        #pragma unroll
        for (int mi = 0; mi < 8; ++mi) {
            const int rloc = wm * 128 + mi * 16 + lq * 4;
            #pragma unroll
            for (int reg = 0; reg < 4; ++reg) {
                const int gr = row0 + rloc + reg;
                float esum = 0.0f;
                #pragma unroll
                for (int ni = 0; ni < 4; ++ni) {
                    const int gc = col0 + wn * 64 + ni * 16 + lm;
                    float s = acc[mi][ni][reg] * INV_T8;
                    if (gc == gr + B_HALF) { pos[gr] = s; pos[gc] = s; }
                    float e = (gc == gr) ? 0.0f : __expf(s);
                    esum += e;
                    ecol[ni] += e;
                }
                esum += __shfl_xor(esum, 1);
                esum += __shfl_xor(esum, 2);
                esum += __shfl_xor(esum, 4);
                esum += __shfl_xor(esum, 8);
                if (lm == 0) rowsum[wn * 256 + rloc + reg] = esum;
            }
        }
        #pragma unroll
        for (int ni = 0; ni < 4; ++ni) {
            ecol[ni] += __shfl_xor(ecol[ni], 16);
            ecol[ni] += __shfl_xor(ecol[ni], 32);
        }
        if (lq == 0 && !isDiag) {
            #pragma unroll
            for (int ni = 0; ni < 4; ++ni)
                colsum[wm * 256 + wn * 64 + ni * 16 + lm] = ecol[ni];
        }
        __syncthreads();
        if (tid < 256) {
            float rs = rowsum[tid] + rowsum[256 + tid]
                     + rowsum[512 + tid] + rowsum[768 + tid];
            atomicAdd(&S[row0 + tid], rs);
            if (!isDiag) {
                float cs = colsum[tid] + colsum[256 + tid];
                atomicAdd(&S[col0 + tid], cs);
            }
        }
    } else {
        // ---- SMALL PATH: 128x128 quadrants of the 16 (rt, rt+16) tiles ----
        const int s = blockIdx.x - NBIG;
        const int p = s >> 2, qr = (s >> 1) & 1, qc = s & 1;
        const int row0 = (2 * p + qr) * 128;
        const int col0 = (2 * p + 32 + qc) * 128;   // never diagonal

        const unsigned char* __restrict__ gA = R8 + (size_t)row0 * D_DIM;
        const unsigned char* __restrict__ gB = R8 + (size_t)col0 * D_DIM;

        floatx4 acc[4][2] = {};

        // waves 0-3 stage A rows (wave*32), waves 4-7 stage B rows ((wave-4)*32)
#define SSTAGE(d, kk) \
        { const int m_ = wave >> 2; \
          const unsigned char* g_ = m_ ? gB : gA; \
          const int w_ = wave & 3; \
          __builtin_amdgcn_global_load_lds( \
            (AS1)(g_ + (size_t)(w_ * 32 + (lane >> 1)) * D_DIM + (kk) + (lane & 1) * 16), \
            (AS3)(&lds8[d][m_][w_ * 1024]), 16, 0, 0); }

        SSTAGE(0, 0)
        asm volatile("s_waitcnt vmcnt(0)" ::: "memory");
        __builtin_amdgcn_s_barrier();

        for (int kt = 0; kt < NKT; ++kt) {
            const int buf = kt & 1;
            const unsigned char* As = &lds8[buf][0][0];
            const unsigned char* Bs = &lds8[buf][1][0];
            if (kt + 1 < NKT) SSTAGE(buf ^ 1, (kt + 1) * 32)

            long af[4], bf[2];
            #pragma unroll
            for (int mi = 0; mi < 4; ++mi)
                af[mi] = *(const long*)(As + (wm * 64 + mi * 16 + lm) * 32 + lq * 8);
            #pragma unroll
            for (int ni = 0; ni < 2; ++ni)
                bf[ni] = *(const long*)(Bs + (wn * 32 + ni * 16 + lm) * 32 + lq * 8);

            __builtin_amdgcn_s_setprio(1);
            #pragma unroll
            for (int mi = 0; mi < 4; ++mi)
                #pragma unroll
                for (int ni = 0; ni < 2; ++ni)
                    acc[mi][ni] = MFMA8(af[mi], bf[ni], acc[mi][ni], 0, 0, 0);
            __builtin_amdgcn_s_setprio(0);

            asm volatile("s_waitcnt vmcnt(0)" ::: "memory");
            __builtin_amdgcn_s_barrier();
        }

        float* rowsum = (float*)&lds8[0][0][0];   // [4][128]
        float* colsum = rowsum + 4 * 128;         // [2][128]
        float ecol[2] = {0.0f, 0.0f};
        #pragma unroll
        for (int mi = 0; mi < 4; ++mi) {
            const int rloc = wm * 64 + mi * 16 + lq * 4;
            #pragma unroll
            for (int reg = 0; reg < 4; ++reg) {
                const int gr = row0 + rloc + reg;
                float esum = 0.0f;
                #pragma unroll
                for (int ni = 0; ni < 2; ++ni) {
                    const int gc = col0 + wn * 32 + ni * 16 + lm;
                    float s = acc[mi][ni][reg] * INV_T8;
                    if (gc == gr + B_HALF) { pos[gr] = s; pos[gc] = s; }
                    float e = __expf(s);     // never on the main diagonal
                    esum += e;
                    ecol[ni] += e;
                }
                esum += __shfl_xor(esum, 1);
                esum += __shfl_xor(esum, 2);
                esum += __shfl_xor(esum, 4);
                esum += __shfl_xor(esum, 8);
                if (lm == 0) rowsum[wn * 128 + rloc + reg] = esum;
            }
        }
        #pragma unroll
        for (int ni = 0; ni < 2; ++ni) {
            ecol[ni] += __shfl_xor(ecol[ni], 16);
            ecol[ni] += __shfl_xor(ecol[ni], 32);
        }
        if (lq == 0) {
            #pragma unroll
            for (int ni = 0; ni < 2; ++ni)
                colsum[wm * 128 + wn * 32 + ni * 16 + lm] = ecol[ni];
        }
        __syncthreads();
        if (tid < 128) {
            float rs = rowsum[tid] + rowsum[128 + tid]
                     + rowsum[256 + tid] + rowsum[384 + tid];
            atomicAdd(&S[row0 + tid], rs);
            float cs = colsum[tid] + colsum[128 + tid];
            atomicAdd(&S[col0 + tid], cs);
        }
    }
}

// Kernel 3: single block; loss = mean(log1p(S * exp(-pos))).
__global__ __launch_bounds__(1024) void finalize_kernel(
    const float* __restrict__ S, const float* __restrict__ pos,
    float* __restrict__ out)
{
    const int tid = threadIdx.x;
    float local = 0.0f;
    #pragma unroll
    for (int i = 0; i < 8; ++i) {
        const int r = i * 1024 + tid;
        local += log1pf(S[r] * __expf(-pos[r]));
    }
    #pragma unroll
    for (int off = 32; off > 0; off >>= 1) local += __shfl_down(local, off);
    __shared__ float ws[16];
    if ((tid & 63) == 0) ws[tid >> 6] = local;
    __syncthreads();
    if (tid == 0) {
        float tot = 0.0f;
        #pragma unroll
        for (int i = 0; i < 16; ++i) tot += ws[i];
        out[0] = tot * (1.0f / 8192.0f);
    }
}

extern "C" void kernel_launch(void* const* d_in, const int* in_sizes, int n_in,
                              void* d_out, int out_size, void* d_ws, size_t ws_size,
                              hipStream_t stream)
{
    const float* z1 = (const float*)d_in[0];
    const float* z2 = (const float*)d_in[1];
    float* out = (float*)d_out;
    char* ws = (char*)d_ws;
    unsigned char* R8 = (unsigned char*)ws;                        // 8 MiB fp8 reps
    float* pos = (float*)(ws + (size_t)8 * 1024 * 1024);           // 32 KiB [8192]
    float* S   = (float*)(ws + (size_t)8 * 1024 * 1024 + 65536);   // 32 KiB [8192]

    normalize_kernel<<<2048, 256, 0, stream>>>(z1, z2, R8, S);
    gemm_lse_kernel<<<NBLK, 512, 0, stream>>>(R8, S, pos);
    finalize_kernel<<<1, 1024, 0, stream>>>(S, pos, out);
}

// Round 14
// 162.992 us; speedup vs baseline: 1.2706x; 1.1291x over previous
//
#include <hip/hip_runtime.h>

#define D_DIM 1024
#define B_HALF 4096
#define NROWS 8192
#define INV_T8 (10.0f / 256.0f)   // temperature 0.1, fp8 stored as 16x values
#define NKT64 16    // 1024 / 64 K-tiles
#define NBIG 512    // 528 upper-tri 256-tiles minus the 16 (rt, rt+16) tiles
#define NBLK 576    // + 64 quadrant 128-tiles dispatched last

typedef float floatx4 __attribute__((ext_vector_type(4)));

#define MFMA8 __builtin_amdgcn_mfma_f32_16x16x32_fp8_fp8
#define AS1 const __attribute__((address_space(1))) unsigned int*
#define AS3 __attribute__((address_space(3))) unsigned int*

// Kernel 1: wave-per-row L2-normalize -> fp8 e4m3 R8 (values x16); zero S.
__global__ __launch_bounds__(256) void normalize_kernel(
    const float* __restrict__ z1, const float* __restrict__ z2,
    unsigned char* __restrict__ R8, float* __restrict__ S)
{
    const int tid = threadIdx.x;
    const int lane = tid & 63;
    const int row = blockIdx.x * 4 + (tid >> 6);
    const float* src = (row < B_HALF) ? (z1 + (size_t)row * D_DIM)
                                      : (z2 + (size_t)(row - B_HALF) * D_DIM);
    const float4* s4 = (const float4*)src;
    float4 v0 = s4[lane], v1 = s4[64 + lane], v2 = s4[128 + lane], v3 = s4[192 + lane];
    if (lane == 0) S[row] = 0.0f;
    float ss = v0.x*v0.x + v0.y*v0.y + v0.z*v0.z + v0.w*v0.w
             + v1.x*v1.x + v1.y*v1.y + v1.z*v1.z + v1.w*v1.w
             + v2.x*v2.x + v2.y*v2.y + v2.z*v2.z + v2.w*v2.w
             + v3.x*v3.x + v3.y*v3.y + v3.z*v3.z + v3.w*v3.w;
    ss += __shfl_xor(ss, 1);
    ss += __shfl_xor(ss, 2);
    ss += __shfl_xor(ss, 4);
    ss += __shfl_xor(ss, 8);
    ss += __shfl_xor(ss, 16);
    ss += __shfl_xor(ss, 32);
    float scale = 16.0f / fmaxf(sqrtf(ss), 1e-12f);   // x16: clear of e4m3 denormals
    int* dst = (int*)(R8 + (size_t)row * D_DIM);
    float4 vv[4] = {v0, v1, v2, v3};
    #pragma unroll
    for (int i = 0; i < 4; ++i) {
        int w = __builtin_amdgcn_cvt_pk_fp8_f32(vv[i].x * scale, vv[i].y * scale, 0, 0);
        w = __builtin_amdgcn_cvt_pk_fp8_f32(vv[i].z * scale, vv[i].w * scale, w, 1);
        dst[i * 64 + lane] = w;
    }
}

// Kernel 2, mixed grid, fp8 operands, BK=64 (64 B rows -> r10-proven swizzle):
//  blocks [0,512): 256x256 tiles (16 pos-band holes skipped). A+B fp8 in
//    64 KiB double-buffered LDS (2 blocks/CU). Stage: 16B slot s holds
//    global slot s ^ ((row>>1)&3) (pre-swizzled source, linear LDS dest).
//    Read: granule g' = g ^ (((lm>>1)&3)<<1) -> bank-pair 8*(lm&1)+(g^2c)
//    distinct per (lm&1,c) class = 2-way max (free). One vmcnt(0)+barrier
//    per 64-K-tile (16 total, half of r13's 32).
//  blocks [512,576): 64 128x128 quadrants of the 16 pos-band tiles, last.
//  Epilogue: row/col exp-sums reduced in LDS, atomicAdd into S.
__global__ __launch_bounds__(512, 2) void gemm_lse_kernel(
    const unsigned char* __restrict__ R8,
    float* __restrict__ S, float* __restrict__ pos)
{
    __shared__ unsigned char lds8[2][2][256 * 64];   // 64 KiB

    const int tid = threadIdx.x;
    const int wave = tid >> 6, lane = tid & 63;
    const int lm = lane & 15, lq = lane >> 4;
    const int wm = wave >> 2, wn = wave & 3;         // 2 x 4 wave grid
    // staging lane map: one issue = 16 rows x 4 slots (16B); involution
    const int sRow = lane >> 2;                      // 0..15
    const int sCol = (lane & 3) ^ ((sRow >> 1) & 3); // swizzled global 16B slot
    // read-side swizzled byte offsets for k-granules lq and 4+lq
    const int gswz = ((lm >> 1) & 3) << 1;           // even granule XOR
    const int sk0 = (lq ^ gswz) * 8;
    const int sk1 = ((4 + lq) ^ gswz) * 8;

    if (blockIdx.x < NBIG) {
        // ---- BIG PATH: 256x256, BK=64 ----
        int t = blockIdx.x;
        #pragma unroll
        for (int i = 0; i < 16; ++i) {               // skip the 16 holes
            const int h = 32 * i - (i * (i - 1)) / 2 + 16;
            if (t >= h) ++t;
        }
        int rt = 0;
        while (t >= 32 - rt) { t -= 32 - rt; ++rt; }
        const int ct = rt + t;
        const bool isDiag = (rt == ct);
        const int row0 = rt * 256, col0 = ct * 256;

        const unsigned char* __restrict__ gA = R8 + (size_t)row0 * D_DIM;
        const unsigned char* __restrict__ gB = R8 + (size_t)col0 * D_DIM;

        floatx4 acc[8][4] = {};

#define BSTAGE(d, kk) \
        { _Pragma("unroll") for (int i = 0; i < 2; ++i) { \
            __builtin_amdgcn_global_load_lds( \
              (AS1)(gA + (size_t)(wave * 32 + i * 16 + sRow) * D_DIM + (kk) + sCol * 16), \
              (AS3)(&lds8[d][0][(wave * 32 + i * 16) * 64]), 16, 0, 0); \
            __builtin_amdgcn_global_load_lds( \
              (AS1)(gB + (size_t)(wave * 32 + i * 16 + sRow) * D_DIM + (kk) + sCol * 16), \
              (AS3)(&lds8[d][1][(wave * 32 + i * 16) * 64]), 16, 0, 0); } }

        BSTAGE(0, 0)
        asm volatile("s_waitcnt vmcnt(0)" ::: "memory");
        __builtin_amdgcn_s_barrier();

        for (int kt = 0; kt < NKT64; ++kt) {
            const int buf = kt & 1;
            const unsigned char* As = &lds8[buf][0][0];
            const unsigned char* Bs = &lds8[buf][1][0];
            if (kt + 1 < NKT64) BSTAGE(buf ^ 1, (kt + 1) * 64)

            long af[8][2], bf[4][2];
            #pragma unroll
            for (int mi = 0; mi < 8; ++mi) {
                const int r = (wm * 128 + mi * 16 + lm) * 64;
                af[mi][0] = *(const long*)(As + r + sk0);
                af[mi][1] = *(const long*)(As + r + sk1);
            }
            #pragma unroll
            for (int ni = 0; ni < 4; ++ni) {
                const int r = (wn * 64 + ni * 16 + lm) * 64;
                bf[ni][0] = *(const long*)(Bs + r + sk0);
                bf[ni][1] = *(const long*)(Bs + r + sk1);
            }

            __builtin_amdgcn_s_setprio(1);
            #pragma unroll
            for (int mi = 0; mi < 8; ++mi)
                #pragma unroll
                for (int ni = 0; ni < 4; ++ni) {
                    acc[mi][ni] = MFMA8(af[mi][0], bf[ni][0], acc[mi][ni], 0, 0, 0);
                    acc[mi][ni] = MFMA8(af[mi][1], bf[ni][1], acc[mi][ni], 0, 0, 0);
                }
            __builtin_amdgcn_s_setprio(0);

            asm volatile("s_waitcnt vmcnt(0)" ::: "memory");
            __builtin_amdgcn_s_barrier();
        }

        float* rowsum = (float*)&lds8[0][0][0];   // [4][256]
        float* colsum = rowsum + 4 * 256;         // [2][256]
        float ecol[4] = {0.0f, 0.0f, 0.0f, 0.0f};
        #pragma unroll
        for (int mi = 0; mi < 8; ++mi) {
            const int rloc = wm * 128 + mi * 16 + lq * 4;
            #pragma unroll
            for (int reg = 0; reg < 4; ++reg) {
                const int gr = row0 + rloc + reg;
                float esum = 0.0f;
                #pragma unroll
                for (int ni = 0; ni < 4; ++ni) {
                    const int gc = col0 + wn * 64 + ni * 16 + lm;
                    float s = acc[mi][ni][reg] * INV_T8;
                    if (gc == gr + B_HALF) { pos[gr] = s; pos[gc] = s; }
                    float e = (gc == gr) ? 0.0f : __expf(s);
                    esum += e;
                    ecol[ni] += e;
                }
                esum += __shfl_xor(esum, 1);
                esum += __shfl_xor(esum, 2);
                esum += __shfl_xor(esum, 4);
                esum += __shfl_xor(esum, 8);
                if (lm == 0) rowsum[wn * 256 + rloc + reg] = esum;
            }
        }
        #pragma unroll
        for (int ni = 0; ni < 4; ++ni) {
            ecol[ni] += __shfl_xor(ecol[ni], 16);
            ecol[ni] += __shfl_xor(ecol[ni], 32);
        }
        if (lq == 0 && !isDiag) {
            #pragma unroll
            for (int ni = 0; ni < 4; ++ni)
                colsum[wm * 256 + wn * 64 + ni * 16 + lm] = ecol[ni];
        }
        __syncthreads();
        if (tid < 256) {
            float rs = rowsum[tid] + rowsum[256 + tid]
                     + rowsum[512 + tid] + rowsum[768 + tid];
            atomicAdd(&S[row0 + tid], rs);
            if (!isDiag) {
                float cs = colsum[tid] + colsum[256 + tid];
                atomicAdd(&S[col0 + tid], cs);
            }
        }
    } else {
        // ---- SMALL PATH: 128x128 quadrants of the 16 (rt, rt+16) tiles ----
        const int s = blockIdx.x - NBIG;
        const int p = s >> 2, qr = (s >> 1) & 1, qc = s & 1;
        const int row0 = (2 * p + qr) * 128;
        const int col0 = (2 * p + 32 + qc) * 128;   // never diagonal

        const unsigned char* __restrict__ gA = R8 + (size_t)row0 * D_DIM;
        const unsigned char* __restrict__ gB = R8 + (size_t)col0 * D_DIM;

        floatx4 acc[4][2] = {};

        // waves 0-3 stage A (2 issues of 16 rows), waves 4-7 stage B
#define SSTAGE(d, kk) \
        { const int m_ = wave >> 2; \
          const unsigned char* g_ = m_ ? gB : gA; \
          const int w_ = wave & 3; \
          _Pragma("unroll") for (int i = 0; i < 2; ++i) { \
            __builtin_amdgcn_global_load_lds( \
              (AS1)(g_ + (size_t)(w_ * 32 + i * 16 + sRow) * D_DIM + (kk) + sCol * 16), \
              (AS3)(&lds8[d][m_][(w_ * 32 + i * 16) * 64]), 16, 0, 0); } }

        SSTAGE(0, 0)
        asm volatile("s_waitcnt vmcnt(0)" ::: "memory");
        __builtin_amdgcn_s_barrier();

        for (int kt = 0; kt < NKT64; ++kt) {
            const int buf = kt & 1;
            const unsigned char* As = &lds8[buf][0][0];
            const unsigned char* Bs = &lds8[buf][1][0];
            if (kt + 1 < NKT64) SSTAGE(buf ^ 1, (kt + 1) * 64)

            long af[4][2], bf[2][2];
            #pragma unroll
            for (int mi = 0; mi < 4; ++mi) {
                const int r = (wm * 64 + mi * 16 + lm) * 64;
                af[mi][0] = *(const long*)(As + r + sk0);
                af[mi][1] = *(const long*)(As + r + sk1);
            }
            #pragma unroll
            for (int ni = 0; ni < 2; ++ni) {
                const int r = (wn * 32 + ni * 16 + lm) * 64;
                bf[ni][0] = *(const long*)(Bs + r + sk0);
                bf[ni][1] = *(const long*)(Bs + r + sk1);
            }

            __builtin_amdgcn_s_setprio(1);
            #pragma unroll
            for (int mi = 0; mi < 4; ++mi)
                #pragma unroll
                for (int ni = 0; ni < 2; ++ni) {
                    acc[mi][ni] = MFMA8(af[mi][0], bf[ni][0], acc[mi][ni], 0, 0, 0);
                    acc[mi][ni] = MFMA8(af[mi][1], bf[ni][1], acc[mi][ni], 0, 0, 0);
                }
            __builtin_amdgcn_s_setprio(0);

            asm volatile("s_waitcnt vmcnt(0)" ::: "memory");
            __builtin_amdgcn_s_barrier();
        }

        float* rowsum = (float*)&lds8[0][0][0];   // [4][128]
        float* colsum = rowsum + 4 * 128;         // [2][128]
        float ecol[2] = {0.0f, 0.0f};
        #pragma unroll
        for (int mi = 0; mi < 4; ++mi) {
            const int rloc = wm * 64 + mi * 16 + lq * 4;
            #pragma unroll
            for (int reg = 0; reg < 4; ++reg) {
                const int gr = row0 + rloc + reg;
                float esum = 0.0f;
                #pragma unroll
                for (int ni = 0; ni < 2; ++ni) {
                    const int gc = col0 + wn * 32 + ni * 16 + lm;
                    float s = acc[mi][ni][reg] * INV_T8;
                    if (gc == gr + B_HALF) { pos[gr] = s; pos[gc] = s; }
                    float e = __expf(s);     // never on the main diagonal
                    esum += e;
                    ecol[ni] += e;
                }
                esum += __shfl_xor(esum, 1);
                esum += __shfl_xor(esum, 2);
                esum += __shfl_xor(esum, 4);
                esum += __shfl_xor(esum, 8);
                if (lm == 0) rowsum[wn * 128 + rloc + reg] = esum;
            }
        }
        #pragma unroll
        for (int ni = 0; ni < 2; ++ni) {
            ecol[ni] += __shfl_xor(ecol[ni], 16);
            ecol[ni] += __shfl_xor(ecol[ni], 32);
        }
        if (lq == 0) {
            #pragma unroll
            for (int ni = 0; ni < 2; ++ni)
                colsum[wm * 128 + wn * 32 + ni * 16 + lm] = ecol[ni];
        }
        __syncthreads();
        if (tid < 128) {
            float rs = rowsum[tid] + rowsum[128 + tid]
                     + rowsum[256 + tid] + rowsum[384 + tid];
            atomicAdd(&S[row0 + tid], rs);
            float cs = colsum[tid] + colsum[128 + tid];
            atomicAdd(&S[col0 + tid], cs);
        }
    }
}

// Kernel 3: single block; loss = mean(log1p(S * exp(-pos))).
__global__ __launch_bounds__(1024) void finalize_kernel(
    const float* __restrict__ S, const float* __restrict__ pos,
    float* __restrict__ out)
{
    const int tid = threadIdx.x;
    float local = 0.0f;
    #pragma unroll
    for (int i = 0; i < 8; ++i) {
        const int r = i * 1024 + tid;
        local += log1pf(S[r] * __expf(-pos[r]));
    }
    #pragma unroll
    for (int off = 32; off > 0; off >>= 1) local += __shfl_down(local, off);
    __shared__ float ws[16];
    if ((tid & 63) == 0) ws[tid >> 6] = local;
    __syncthreads();
    if (tid == 0) {
        float tot = 0.0f;
        #pragma unroll
        for (int i = 0; i < 16; ++i) tot += ws[i];
        out[0] = tot * (1.0f / 8192.0f);
    }
}

extern "C" void kernel_launch(void* const* d_in, const int* in_sizes, int n_in,
                              void* d_out, int out_size, void* d_ws, size_t ws_size,
                              hipStream_t stream)
{
    const float* z1 = (const float*)d_in[0];
    const float* z2 = (const float*)d_in[1];
    float* out = (float*)d_out;
    char* ws = (char*)d_ws;
    unsigned char* R8 = (unsigned char*)ws;                        // 8 MiB fp8 reps
    float* pos = (float*)(ws + (size_t)8 * 1024 * 1024);           // 32 KiB [8192]
    float* S   = (float*)(ws + (size_t)8 * 1024 * 1024 + 65536);   // 32 KiB [8192]

    normalize_kernel<<<2048, 256, 0, stream>>>(z1, z2, R8, S);
    gemm_lse_kernel<<<NBLK, 512, 0, stream>>>(R8, S, pos);
    finalize_kernel<<<1, 1024, 0, stream>>>(S, pos, out);
}

// Round 15
// 150.298 us; speedup vs baseline: 1.3779x; 1.0845x over previous
//
#include <hip/hip_runtime.h>

#define D_DIM 1024
#define B_HALF 4096
#define NROWS 8192
#define INV_T8 (10.0f / 256.0f)   // temperature 0.1, fp8 stored as 16x values
#define NKT64 16    // 1024 / 64 K-tiles
#define NBIG 512    // 528 upper-tri 256-tiles minus the 16 (rt, rt+16) tiles
#define NBLK 576    // + 64 quadrant 128-tiles dispatched last

typedef float floatx4 __attribute__((ext_vector_type(4)));
typedef long longx2 __attribute__((ext_vector_type(2)));

#define MFMA8 __builtin_amdgcn_mfma_f32_16x16x32_fp8_fp8
#define AS1 const __attribute__((address_space(1))) unsigned int*
#define AS3 __attribute__((address_space(3))) unsigned int*

// Kernel 1: wave-per-row L2-normalize -> fp8 e4m3 R8 (values x16), written
// K-INTERLEAVED: within each 64B k-chunk, 16B slot s holds k-granules
// (s, s+4), so one ds_read_b128 later yields both K=32 MFMA operands.
// Write index is a lane-bit permutation (bijective, coalesced).
__global__ __launch_bounds__(256) void normalize_kernel(
    const float* __restrict__ z1, const float* __restrict__ z2,
    unsigned char* __restrict__ R8, float* __restrict__ S)
{
    const int tid = threadIdx.x;
    const int lane = tid & 63;
    const int row = blockIdx.x * 4 + (tid >> 6);
    const float* src = (row < B_HALF) ? (z1 + (size_t)row * D_DIM)
                                      : (z2 + (size_t)(row - B_HALF) * D_DIM);
    const float4* s4 = (const float4*)src;
    float4 v0 = s4[lane], v1 = s4[64 + lane], v2 = s4[128 + lane], v3 = s4[192 + lane];
    if (lane == 0) S[row] = 0.0f;
    float ss = v0.x*v0.x + v0.y*v0.y + v0.z*v0.z + v0.w*v0.w
             + v1.x*v1.x + v1.y*v1.y + v1.z*v1.z + v1.w*v1.w
             + v2.x*v2.x + v2.y*v2.y + v2.z*v2.z + v2.w*v2.w
             + v3.x*v3.x + v3.y*v3.y + v3.z*v3.z + v3.w*v3.w;
    ss += __shfl_xor(ss, 1);
    ss += __shfl_xor(ss, 2);
    ss += __shfl_xor(ss, 4);
    ss += __shfl_xor(ss, 8);
    ss += __shfl_xor(ss, 16);
    ss += __shfl_xor(ss, 32);
    float scale = 16.0f / fmaxf(sqrtf(ss), 1e-12f);   // x16: clear of e4m3 denormals
    int* dst = (int*)(R8 + (size_t)row * D_DIM);
    // interleave map for the 4B word this lane produces at orig p=i*256+lane*4:
    //   granule g=(lane>>1)&7 -> slot g&3, half g>>2
    const int dbase = ((lane >> 4) * 16) + (((lane >> 1) & 3) * 4)
                    + (((lane >> 3) & 1) * 2) + (lane & 1);
    float4 vv[4] = {v0, v1, v2, v3};
    #pragma unroll
    for (int i = 0; i < 4; ++i) {
        int w = __builtin_amdgcn_cvt_pk_fp8_f32(vv[i].x * scale, vv[i].y * scale, 0, 0);
        w = __builtin_amdgcn_cvt_pk_fp8_f32(vv[i].z * scale, vv[i].w * scale, w, 1);
        dst[i * 64 + dbase] = w;
    }
}

// Kernel 2, mixed grid, fp8 K-interleaved operands, BK=64:
//  blocks [0,512): 256x256 tiles (16 pos-band holes skipped). A+B fp8 in
//    64 KiB double-buffered LDS (2 blocks/CU). Stage: 16B slot s of row r
//    holds global slot s ^ ((r>>1)&3) (pre-swizzled source, linear dest).
//    Read: ONE ds_read_b128 per fragment pair at slot lq ^ ((lm>>1)&3)
//    -> r10-proven zero-conflict geometry (quad = 4*lm0 + slot, full
//    coverage per quarter-wave). .x = k-sub0 operand, .y = k-sub1.
//  blocks [512,576): 64 128x128 quadrants of the 16 pos-band tiles, last.
//  Epilogue: row/col exp-sums reduced in LDS, atomicAdd into S.
__global__ __launch_bounds__(512, 2) void gemm_lse_kernel(
    const unsigned char* __restrict__ R8,
    float* __restrict__ S, float* __restrict__ pos)
{
    __shared__ unsigned char lds8[2][2][256 * 64];   // 64 KiB

    const int tid = threadIdx.x;
    const int wave = tid >> 6, lane = tid & 63;
    const int lm = lane & 15, lq = lane >> 4;
    const int wm = wave >> 2, wn = wave & 3;         // 2 x 4 wave grid
    // staging lane map: one issue = 16 rows x 4 slots (16B); involution
    const int sRow = lane >> 2;                      // 0..15
    const int sCol = (lane & 3) ^ ((sRow >> 1) & 3); // swizzled global 16B slot
    // read-side swizzled slot byte offset (one b128 per fragment pair)
    const int sk = (lq ^ ((lm >> 1) & 3)) * 16;

    if (blockIdx.x < NBIG) {
        // ---- BIG PATH: 256x256, BK=64 ----
        int t = blockIdx.x;
        #pragma unroll
        for (int i = 0; i < 16; ++i) {               // skip the 16 holes
            const int h = 32 * i - (i * (i - 1)) / 2 + 16;
            if (t >= h) ++t;
        }
        int rt = 0;
        while (t >= 32 - rt) { t -= 32 - rt; ++rt; }
        const int ct = rt + t;
        const bool isDiag = (rt == ct);
        const int row0 = rt * 256, col0 = ct * 256;

        const unsigned char* __restrict__ gA = R8 + (size_t)row0 * D_DIM;
        const unsigned char* __restrict__ gB = R8 + (size_t)col0 * D_DIM;

        floatx4 acc[8][4] = {};

#define BSTAGE(d, kk) \
        { _Pragma("unroll") for (int i = 0; i < 2; ++i) { \
            __builtin_amdgcn_global_load_lds( \
              (AS1)(gA + (size_t)(wave * 32 + i * 16 + sRow) * D_DIM + (kk) + sCol * 16), \
              (AS3)(&lds8[d][0][(wave * 32 + i * 16) * 64]), 16, 0, 0); \
            __builtin_amdgcn_global_load_lds( \
              (AS1)(gB + (size_t)(wave * 32 + i * 16 + sRow) * D_DIM + (kk) + sCol * 16), \
              (AS3)(&lds8[d][1][(wave * 32 + i * 16) * 64]), 16, 0, 0); } }

        BSTAGE(0, 0)
        asm volatile("s_waitcnt vmcnt(0)" ::: "memory");
        __builtin_amdgcn_s_barrier();

        for (int kt = 0; kt < NKT64; ++kt) {
            const int buf = kt & 1;
            const unsigned char* As = &lds8[buf][0][0];
            const unsigned char* Bs = &lds8[buf][1][0];
            if (kt + 1 < NKT64) BSTAGE(buf ^ 1, (kt + 1) * 64)

            longx2 af[8], bf[4];
            #pragma unroll
            for (int mi = 0; mi < 8; ++mi)
                af[mi] = *(const longx2*)(As + (wm * 128 + mi * 16 + lm) * 64 + sk);
            #pragma unroll
            for (int ni = 0; ni < 4; ++ni)
                bf[ni] = *(const longx2*)(Bs + (wn * 64 + ni * 16 + lm) * 64 + sk);

            __builtin_amdgcn_s_setprio(1);
            #pragma unroll
            for (int mi = 0; mi < 8; ++mi)
                #pragma unroll
                for (int ni = 0; ni < 4; ++ni) {
                    acc[mi][ni] = MFMA8(af[mi][0], bf[ni][0], acc[mi][ni], 0, 0, 0);
                    acc[mi][ni] = MFMA8(af[mi][1], bf[ni][1], acc[mi][ni], 0, 0, 0);
                }
            __builtin_amdgcn_s_setprio(0);

            asm volatile("s_waitcnt vmcnt(0)" ::: "memory");
            __builtin_amdgcn_s_barrier();
        }

        float* rowsum = (float*)&lds8[0][0][0];   // [4][256]
        float* colsum = rowsum + 4 * 256;         // [2][256]
        float ecol[4] = {0.0f, 0.0f, 0.0f, 0.0f};
        #pragma unroll
        for (int mi = 0; mi < 8; ++mi) {
            const int rloc = wm * 128 + mi * 16 + lq * 4;
            #pragma unroll
            for (int reg = 0; reg < 4; ++reg) {
                const int gr = row0 + rloc + reg;
                float esum = 0.0f;
                #pragma unroll
                for (int ni = 0; ni < 4; ++ni) {
                    const int gc = col0 + wn * 64 + ni * 16 + lm;
                    float s = acc[mi][ni][reg] * INV_T8;
                    if (gc == gr + B_HALF) { pos[gr] = s; pos[gc] = s; }
                    float e = (gc == gr) ? 0.0f : __expf(s);
                    esum += e;
                    ecol[ni] += e;
                }
                esum += __shfl_xor(esum, 1);
                esum += __shfl_xor(esum, 2);
                esum += __shfl_xor(esum, 4);
                esum += __shfl_xor(esum, 8);
                if (lm == 0) rowsum[wn * 256 + rloc + reg] = esum;
            }
        }
        #pragma unroll
        for (int ni = 0; ni < 4; ++ni) {
            ecol[ni] += __shfl_xor(ecol[ni], 16);
            ecol[ni] += __shfl_xor(ecol[ni], 32);
        }
        if (lq == 0 && !isDiag) {
            #pragma unroll
            for (int ni = 0; ni < 4; ++ni)
                colsum[wm * 256 + wn * 64 + ni * 16 + lm] = ecol[ni];
        }
        __syncthreads();
        if (tid < 256) {
            float rs = rowsum[tid] + rowsum[256 + tid]
                     + rowsum[512 + tid] + rowsum[768 + tid];
            atomicAdd(&S[row0 + tid], rs);
            if (!isDiag) {
                float cs = colsum[tid] + colsum[256 + tid];
                atomicAdd(&S[col0 + tid], cs);
            }
        }
    } else {
        // ---- SMALL PATH: 128x128 quadrants of the 16 (rt, rt+16) tiles ----
        const int s = blockIdx.x - NBIG;
        const int p = s >> 2, qr = (s >> 1) & 1, qc = s & 1;
        const int row0 = (2 * p + qr) * 128;
        const int col0 = (2 * p + 32 + qc) * 128;   // never diagonal

        const unsigned char* __restrict__ gA = R8 + (size_t)row0 * D_DIM;
        const unsigned char* __restrict__ gB = R8 + (size_t)col0 * D_DIM;

        floatx4 acc[4][2] = {};

        // waves 0-3 stage A (2 issues of 16 rows), waves 4-7 stage B
#define SSTAGE(d, kk) \
        { const int m_ = wave >> 2; \
          const unsigned char* g_ = m_ ? gB : gA; \
          const int w_ = wave & 3; \
          _Pragma("unroll") for (int i = 0; i < 2; ++i) { \
            __builtin_amdgcn_global_load_lds( \
              (AS1)(g_ + (size_t)(w_ * 32 + i * 16 + sRow) * D_DIM + (kk) + sCol * 16), \
              (AS3)(&lds8[d][m_][(w_ * 32 + i * 16) * 64]), 16, 0, 0); } }

        SSTAGE(0, 0)
        asm volatile("s_waitcnt vmcnt(0)" ::: "memory");
        __builtin_amdgcn_s_barrier();

        for (int kt = 0; kt < NKT64; ++kt) {
            const int buf = kt & 1;
            const unsigned char* As = &lds8[buf][0][0];
            const unsigned char* Bs = &lds8[buf][1][0];
            if (kt + 1 < NKT64) SSTAGE(buf ^ 1, (kt + 1) * 64)

            longx2 af[4], bf[2];
            #pragma unroll
            for (int mi = 0; mi < 4; ++mi)
                af[mi] = *(const longx2*)(As + (wm * 64 + mi * 16 + lm) * 64 + sk);
            #pragma unroll
            for (int ni = 0; ni < 2; ++ni)
                bf[ni] = *(const longx2*)(Bs + (wn * 32 + ni * 16 + lm) * 64 + sk);

            __builtin_amdgcn_s_setprio(1);
            #pragma unroll
            for (int mi = 0; mi < 4; ++mi)
                #pragma unroll
                for (int ni = 0; ni < 2; ++ni) {
                    acc[mi][ni] = MFMA8(af[mi][0], bf[ni][0], acc[mi][ni], 0, 0, 0);
                    acc[mi][ni] = MFMA8(af[mi][1], bf[ni][1], acc[mi][ni], 0, 0, 0);
                }
            __builtin_amdgcn_s_setprio(0);

            asm volatile("s_waitcnt vmcnt(0)" ::: "memory");
            __builtin_amdgcn_s_barrier();
        }

        float* rowsum = (float*)&lds8[0][0][0];   // [4][128]
        float* colsum = rowsum + 4 * 128;         // [2][128]
        float ecol[2] = {0.0f, 0.0f};
        #pragma unroll
        for (int mi = 0; mi < 4; ++mi) {
            const int rloc = wm * 64 + mi * 16 + lq * 4;
            #pragma unroll
            for (int reg = 0; reg < 4; ++reg) {
                const int gr = row0 + rloc + reg;
                float esum = 0.0f;
                #pragma unroll
                for (int ni = 0; ni < 2; ++ni) {
                    const int gc = col0 + wn * 32 + ni * 16 + lm;
                    float s = acc[mi][ni][reg] * INV_T8;
                    if (gc == gr + B_HALF) { pos[gr] = s; pos[gc] = s; }
                    float e = __expf(s);     // never on the main diagonal
                    esum += e;
                    ecol[ni] += e;
                }
                esum += __shfl_xor(esum, 1);
                esum += __shfl_xor(esum, 2);
                esum += __shfl_xor(esum, 4);
                esum += __shfl_xor(esum, 8);
                if (lm == 0) rowsum[wn * 128 + rloc + reg] = esum;
            }
        }
        #pragma unroll
        for (int ni = 0; ni < 2; ++ni) {
            ecol[ni] += __shfl_xor(ecol[ni], 16);
            ecol[ni] += __shfl_xor(ecol[ni], 32);
        }
        if (lq == 0) {
            #pragma unroll
            for (int ni = 0; ni < 2; ++ni)
                colsum[wm * 128 + wn * 32 + ni * 16 + lm] = ecol[ni];
        }
        __syncthreads();
        if (tid < 128) {
            float rs = rowsum[tid] + rowsum[128 + tid]
                     + rowsum[256 + tid] + rowsum[384 + tid];
            atomicAdd(&S[row0 + tid], rs);
            float cs = colsum[tid] + colsum[128 + tid];
            atomicAdd(&S[col0 + tid], cs);
        }
    }
}

// Kernel 3: single block; loss = mean(log1p(S * exp(-pos))).
__global__ __launch_bounds__(1024) void finalize_kernel(
    const float* __restrict__ S, const float* __restrict__ pos,
    float* __restrict__ out)
{
    const int tid = threadIdx.x;
    float local = 0.0f;
    #pragma unroll
    for (int i = 0; i < 8; ++i) {
        const int r = i * 1024 + tid;
        local += log1pf(S[r] * __expf(-pos[r]));
    }
    #pragma unroll
    for (int off = 32; off > 0; off >>= 1) local += __shfl_down(local, off);
    __shared__ float ws[16];
    if ((tid & 63) == 0) ws[tid >> 6] = local;
    __syncthreads();
    if (tid == 0) {
        float tot = 0.0f;
        #pragma unroll
        for (int i = 0; i < 16; ++i) tot += ws[i];
        out[0] = tot * (1.0f / 8192.0f);
    }
}

extern "C" void kernel_launch(void* const* d_in, const int* in_sizes, int n_in,
                              void* d_out, int out_size, void* d_ws, size_t ws_size,
                              hipStream_t stream)
{
    const float* z1 = (const float*)d_in[0];
    const float* z2 = (const float*)d_in[1];
    float* out = (float*)d_out;
    char* ws = (char*)d_ws;
    unsigned char* R8 = (unsigned char*)ws;                        // 8 MiB fp8 reps
    float* pos = (float*)(ws + (size_t)8 * 1024 * 1024);           // 32 KiB [8192]
    float* S   = (float*)(ws + (size_t)8 * 1024 * 1024 + 65536);   // 32 KiB [8192]

    normalize_kernel<<<2048, 256, 0, stream>>>(z1, z2, R8, S);
    gemm_lse_kernel<<<NBLK, 512, 0, stream>>>(R8, S, pos);
    finalize_kernel<<<1, 1024, 0, stream>>>(S, pos, out);
}